// Round 1
// baseline (1112.658 us; speedup 1.0000x reference)
//
#include <hip/hip_runtime.h>

typedef _Float16 f16;
typedef f16  half8 __attribute__((ext_vector_type(8)));
typedef float f32x4 __attribute__((ext_vector_type(4)));

#define B_   32
#define C_   1024
#define HW_  784
#define BQ   64
#define NKC  25   // ceil(784/32): last chunk lane-masked (784 = 768+16, aligns to 8-elem lane groups)

// pack two float4 (8 consecutive f32) into an MFMA half8 fragment
__device__ __forceinline__ half8 pack8(const float4& a, const float4& b) {
  half8 r;
  r[0]=(f16)a.x; r[1]=(f16)a.y; r[2]=(f16)a.z; r[3]=(f16)a.w;
  r[4]=(f16)b.x; r[5]=(f16)b.y; r[6]=(f16)b.z; r[7]=(f16)b.w;
  return r;
}

// Fused channel attention: per WG = (batch b, 64-row block).
// Phase 1: raw scores S = m_rows . m^T  (f16, XOR-swizzled, in LDS)
// Boundary: in-place row softmax (scale 1/32 folded into exp2)
// Phase 2: y = P . m ; out = x + y
__global__ __launch_bounds__(512, 2)
void chanattn_kernel(const float* __restrict__ x, float* __restrict__ out) {
  __shared__ f16 Pl[BQ * C_];   // 128 KiB

  // XCD-aware decode: blocks of the same batch land on the same XCD (i%8 heuristic)
  const int bi   = blockIdx.x;
  const int slot = bi >> 3;                      // 0..63
  const int b    = ((slot >> 4) << 3) | (bi & 7); // 0..31
  const int rb   = slot & 15;                    // 0..15
  const int q0   = rb * BQ;

  const int tid  = threadIdx.x;
  const int w    = tid >> 6;    // wave 0..7
  const int lane = tid & 63;
  const int l15  = lane & 15;
  const int l4   = lane >> 4;   // 0..3

  const float* mb = x + (size_t)b * (C_ * HW_);
  char* Pb = (char*)Pl;

  // ---------------- Phase 1: raw scores ----------------
  {
    const int cw = w * 128;     // this wave's 128 kv-columns
    for (int tile = 0; tile < 2; ++tile) {
      const int c0 = cw + tile * 64;
      f32x4 acc[4][4] = {};     // [row-frag][col-frag], rows 64 x cols 64
      for (int kc = 0; kc < NKC; ++kc) {
        const int k0 = kc * 32 + l4 * 8;
        const bool ok = (k0 < HW_);           // whole-lane mask on last chunk
        half8 afr[4], bfr[4];
#pragma unroll
        for (int rf = 0; rf < 4; ++rf) {
          if (ok) {
            const float4* p = (const float4*)(mb + (q0 + rf*16 + l15) * HW_ + k0);
            afr[rf] = pack8(p[0], p[1]);
          } else {
#pragma unroll
            for (int e = 0; e < 8; ++e) afr[rf][e] = (f16)0.f;
          }
        }
#pragma unroll
        for (int cf = 0; cf < 4; ++cf) {
          if (ok) {
            const float4* p = (const float4*)(mb + (c0 + cf*16 + l15) * HW_ + k0);
            bfr[cf] = pack8(p[0], p[1]);      // B[k][n] = m[n][k]: contiguous in k
          } else {
#pragma unroll
            for (int e = 0; e < 8; ++e) bfr[cf][e] = (f16)0.f;
          }
        }
#pragma unroll
        for (int rf = 0; rf < 4; ++rf)
#pragma unroll
          for (int cf = 0; cf < 4; ++cf)
            acc[rf][cf] = __builtin_amdgcn_mfma_f32_16x16x32_f16(afr[rf], bfr[cf], acc[rf][cf], 0, 0, 0);
      }
      // store raw scores f16 -> LDS, XOR swizzle (row&7)<<4
#pragma unroll
      for (int rf = 0; rf < 4; ++rf)
#pragma unroll
        for (int cf = 0; cf < 4; ++cf)
#pragma unroll
          for (int r = 0; r < 4; ++r) {
            const int row = rf*16 + l4*4 + r;     // C/D layout: col=lane&15, row=(lane>>4)*4+reg
            const int col = c0 + cf*16 + l15;
            int byte = row*2048 + col*2;
            byte ^= (row & 7) << 4;
            *(f16*)(Pb + byte) = (f16)acc[rf][cf][r];
          }
    }
  }
  __syncthreads();

  // ---------------- boundary: in-place softmax, rows w*8..w*8+7 ----------------
  {
    const float ksc = 0.045084223f;   // log2(e) / 32  (scale folded in)
    for (int rr = 0; rr < 8; ++rr) {
      const int row = w*8 + rr;
      const int sw  = (row & 7) << 4;
      char* rbase = Pb + row*2048;
      const int c0 = lane * 32;       // 16 f16 per lane
      half8 v0 = *(half8*)(rbase + ((c0     ) ^ sw));
      half8 v1 = *(half8*)(rbase + ((c0 + 16) ^ sw));
      float f[16];
#pragma unroll
      for (int e = 0; e < 8; ++e) { f[e] = (float)v0[e]; f[e+8] = (float)v1[e]; }
      float mx = f[0];
#pragma unroll
      for (int e = 1; e < 16; ++e) mx = fmaxf(mx, f[e]);
      for (int d = 1; d < 64; d <<= 1) mx = fmaxf(mx, __shfl_xor(mx, d));
      float sum = 0.f;
#pragma unroll
      for (int e = 0; e < 16; ++e) { f[e] = exp2f((f[e] - mx) * ksc); sum += f[e]; }
      for (int d = 1; d < 64; d <<= 1) sum += __shfl_xor(sum, d);
      const float inv = 1.f / sum;
#pragma unroll
      for (int e = 0; e < 8; ++e) { v0[e] = (f16)(f[e]*inv); v1[e] = (f16)(f[e+8]*inv); }
      *(half8*)(rbase + ((c0     ) ^ sw)) = v0;
      *(half8*)(rbase + ((c0 + 16) ^ sw)) = v1;
    }
  }
  __syncthreads();

  // ---------------- Phase 2: y = P . V ; out = x + y ----------------
  {
    f32x4 acc[7][4] = {};   // [d-strip][row-frag]; strips s = w + 8*si over 49 strips of 16
    for (int t = 0; t < 16; ++t) {
      half8 afr[4][2];      // P fragments: rows 64, kv chunk t*64 (two k=32 halves)
#pragma unroll
      for (int rf = 0; rf < 4; ++rf)
#pragma unroll
        for (int kf = 0; kf < 2; ++kf) {
          const int row = rf*16 + l15;          // A layout: row=lane&15, k=(lane>>4)*8+e
          int byte = row*2048 + t*128 + kf*64 + l4*16;
          byte ^= (row & 7) << 4;
          afr[rf][kf] = *(half8*)(Pb + byte);
        }
#pragma unroll
      for (int si = 0; si < 7; ++si) {
        const int s = w + 8*si;
        if (s < 49) {                            // wave-uniform guard
          const int d = s*16 + l15;
#pragma unroll
          for (int kf = 0; kf < 2; ++kf) {
            const int kv = t*64 + kf*32 + l4*8;
            half8 bfr;                           // V[kv][d]: strided gather (fix in later rounds)
#pragma unroll
            for (int e = 0; e < 8; ++e)
              bfr[e] = (f16)mb[(kv + e) * HW_ + d];
#pragma unroll
            for (int rf = 0; rf < 4; ++rf)
              acc[si][rf] = __builtin_amdgcn_mfma_f32_16x16x32_f16(afr[rf][kf], bfr, acc[si][rf], 0, 0, 0);
          }
        }
      }
    }
    // epilogue: out = x + y
#pragma unroll
    for (int si = 0; si < 7; ++si) {
      const int s = w + 8*si;
      if (s < 49) {
        const int d = s*16 + l15;
#pragma unroll
        for (int rf = 0; rf < 4; ++rf)
#pragma unroll
          for (int r = 0; r < 4; ++r) {
            const size_t idx = (size_t)(b*C_ + q0 + rf*16 + l4*4 + r) * HW_ + d;
            out[idx] = x[idx] + acc[si][rf][r];
          }
      }
    }
  }
}

extern "C" void kernel_launch(void* const* d_in, const int* in_sizes, int n_in,
                              void* d_out, int out_size, void* d_ws, size_t ws_size,
                              hipStream_t stream) {
  const float* x = (const float*)d_in[0];
  float* out = (float*)d_out;
  chanattn_kernel<<<dim3(512), dim3(512), 0, stream>>>(x, out);
}

// Round 2
// 302.514 us; speedup vs baseline: 3.6780x; 3.6780x over previous
//
#include <hip/hip_runtime.h>

typedef _Float16 f16;
typedef f16  half8 __attribute__((ext_vector_type(8)));
typedef float f32x4 __attribute__((ext_vector_type(4)));

#define B_   32
#define C_   1024
#define HW_  784
#define BQ   64
#define NKC  25   // ceil(784/32): last chunk lane-masked

// ---------------------------------------------------------------------------
// Prep: m16[b][c][hw] = (f16)x, and mT[b][hw][c] = (f16)x transposed.
// 64(c) x 64(hw) tiles through LDS; all global accesses coalesced.
// ---------------------------------------------------------------------------
__global__ __launch_bounds__(256)
void prep_kernel(const float* __restrict__ x, f16* __restrict__ m16, f16* __restrict__ mT) {
  __shared__ f16 lt[64][72];   // pad 72: 144B row stride (16B-aligned, 4-mod-32 banks)
  const int bi = blockIdx.x;               // b*208 + ct*13 + ht
  const int ht = bi % 13;
  const int ct = (bi / 13) & 15;
  const int b  = bi / 208;
  const int h0 = ht * 64, c0 = ct * 64;
  const int t = threadIdx.x, r = t >> 2, q = t & 3;
  const size_t base = (size_t)b * (C_ * HW_);

  const int hq = h0 + q * 16;              // 784 = 49*16: chunks are all-or-nothing
  if (hq < HW_) {
    const float* src = x + base + (size_t)(c0 + r) * HW_ + hq;
    float f[16];
#pragma unroll
    for (int j = 0; j < 4; ++j) ((float4*)f)[j] = ((const float4*)src)[j];
    f16 h[16];
#pragma unroll
    for (int j = 0; j < 16; ++j) h[j] = (f16)f[j];
    f16* dm = m16 + base + (size_t)(c0 + r) * HW_ + hq;
    *(half8*)dm = *(half8*)h;
    *(half8*)(dm + 8) = *(half8*)(h + 8);
    *(half8*)&lt[r][q * 16]     = *(half8*)h;
    *(half8*)&lt[r][q * 16 + 8] = *(half8*)(h + 8);
  }
  __syncthreads();
  if (h0 + r < HW_) {
    f16 h[16];
#pragma unroll
    for (int j = 0; j < 16; ++j) h[j] = lt[q * 16 + j][r];
    f16* dst = mT + (size_t)b * (HW_ * C_) + (size_t)(h0 + r) * C_ + c0 + q * 16;
    *(half8*)dst = *(half8*)h;
    *(half8*)(dst + 8) = *(half8*)(h + 8);
  }
}

// ---------------------------------------------------------------------------
// Main fused kernel: per WG = (batch, 64-row block).
// Phase 1: S = m16_rows . m16^T (f16 frags, 16B loads), raw f16 -> swizzled LDS
// Boundary: in-place row softmax (1/32 scale folded into exp2)
// Phase 2: y = P . V with B-frags as 16B loads from mT; out = x + y
// ---------------------------------------------------------------------------
__global__ __launch_bounds__(512, 2)
void chanattn_main(const float* __restrict__ x, const f16* __restrict__ m16,
                   const f16* __restrict__ mT, float* __restrict__ out) {
  __shared__ f16 Pl[BQ * C_];   // 128 KiB

  const int bi   = blockIdx.x;
  const int slot = bi >> 3;
  const int b    = ((slot >> 4) << 3) | (bi & 7);
  const int rb   = slot & 15;
  const int q0   = rb * BQ;

  const int tid  = threadIdx.x;
  const int w    = tid >> 6;
  const int lane = tid & 63;
  const int l15  = lane & 15;
  const int l4   = lane >> 4;

  const f16* m16b = m16 + (size_t)b * (C_ * HW_);
  const f16* mTb  = mT  + (size_t)b * (HW_ * C_);
  char* Pb = (char*)Pl;

  // ---------------- Phase 1: raw scores ----------------
  {
    const int cw = w * 128;
    for (int tile = 0; tile < 2; ++tile) {
      const int c0 = cw + tile * 64;
      f32x4 acc[4][4] = {};
      for (int kc = 0; kc < NKC; ++kc) {
        const int k0 = kc * 32 + l4 * 8;
        const bool ok = (k0 < HW_);
        half8 afr[4], bfr[4];
#pragma unroll
        for (int rf = 0; rf < 4; ++rf) {
          if (ok) afr[rf] = *(const half8*)(m16b + (size_t)(q0 + rf*16 + l15) * HW_ + k0);
          else { 
#pragma unroll
            for (int e = 0; e < 8; ++e) afr[rf][e] = (f16)0.f; }
        }
#pragma unroll
        for (int cf = 0; cf < 4; ++cf) {
          if (ok) bfr[cf] = *(const half8*)(m16b + (size_t)(c0 + cf*16 + l15) * HW_ + k0);
          else {
#pragma unroll
            for (int e = 0; e < 8; ++e) bfr[cf][e] = (f16)0.f; }
        }
#pragma unroll
        for (int rf = 0; rf < 4; ++rf)
#pragma unroll
          for (int cf = 0; cf < 4; ++cf)
            acc[rf][cf] = __builtin_amdgcn_mfma_f32_16x16x32_f16(afr[rf], bfr[cf], acc[rf][cf], 0, 0, 0);
      }
#pragma unroll
      for (int rf = 0; rf < 4; ++rf)
#pragma unroll
        for (int cf = 0; cf < 4; ++cf)
#pragma unroll
          for (int r = 0; r < 4; ++r) {
            const int row = rf*16 + l4*4 + r;
            const int col = c0 + cf*16 + l15;
            int byte = row*2048 + col*2;
            byte ^= (row & 7) << 4;
            *(f16*)(Pb + byte) = (f16)acc[rf][cf][r];
          }
    }
  }
  __syncthreads();

  // ---------------- boundary: softmax rows w*8..w*8+7 ----------------
  {
    const float ksc = 0.045084223f;   // log2(e)/32
    for (int rr = 0; rr < 8; ++rr) {
      const int row = w*8 + rr;
      const int sw  = (row & 7) << 4;
      char* rbase = Pb + row*2048;
      const int c0 = lane * 32;
      half8 v0 = *(half8*)(rbase + ((c0     ) ^ sw));
      half8 v1 = *(half8*)(rbase + ((c0 + 16) ^ sw));
      float f[16];
#pragma unroll
      for (int e = 0; e < 8; ++e) { f[e] = (float)v0[e]; f[e+8] = (float)v1[e]; }
      float mx = f[0];
#pragma unroll
      for (int e = 1; e < 16; ++e) mx = fmaxf(mx, f[e]);
      for (int d = 1; d < 64; d <<= 1) mx = fmaxf(mx, __shfl_xor(mx, d));
      float sum = 0.f;
#pragma unroll
      for (int e = 0; e < 16; ++e) { f[e] = exp2f((f[e] - mx) * ksc); sum += f[e]; }
      for (int d = 1; d < 64; d <<= 1) sum += __shfl_xor(sum, d);
      const float inv = 1.f / sum;
#pragma unroll
      for (int e = 0; e < 8; ++e) { v0[e] = (f16)(f[e]*inv); v1[e] = (f16)(f[e+8]*inv); }
      *(half8*)(rbase + ((c0     ) ^ sw)) = v0;
      *(half8*)(rbase + ((c0 + 16) ^ sw)) = v1;
    }
  }
  __syncthreads();

  // ---------------- Phase 2: y = P . V ; out = x + y ----------------
  {
    f32x4 acc[7][4] = {};
    for (int t = 0; t < 16; ++t) {
      half8 afr[4][2];
#pragma unroll
      for (int rf = 0; rf < 4; ++rf)
#pragma unroll
        for (int kf = 0; kf < 2; ++kf) {
          const int row = rf*16 + l15;
          int byte = row*2048 + t*128 + kf*64 + l4*16;
          byte ^= (row & 7) << 4;
          afr[rf][kf] = *(half8*)(Pb + byte);
        }
#pragma unroll
      for (int si = 0; si < 7; ++si) {
        const int s = w + 8*si;
        if (s < 49) {
          const int d = s*16 + l15;
          const f16* vrow = mTb + (size_t)d * C_;
#pragma unroll
          for (int kf = 0; kf < 2; ++kf) {
            const int kv0 = t*64 + kf*32 + l4*8;
            half8 bfr = *(const half8*)(vrow + kv0);   // contiguous in kv
#pragma unroll
            for (int rf = 0; rf < 4; ++rf)
              acc[si][rf] = __builtin_amdgcn_mfma_f32_16x16x32_f16(afr[rf][kf], bfr, acc[si][rf], 0, 0, 0);
          }
        }
      }
    }
#pragma unroll
    for (int si = 0; si < 7; ++si) {
      const int s = w + 8*si;
      if (s < 49) {
        const int d = s*16 + l15;
#pragma unroll
        for (int rf = 0; rf < 4; ++rf)
#pragma unroll
          for (int r = 0; r < 4; ++r) {
            const size_t idx = (size_t)(b*C_ + q0 + rf*16 + l4*4 + r) * HW_ + d;
            out[idx] = x[idx] + acc[si][rf][r];
          }
      }
    }
  }
}

// ---------------------------------------------------------------------------
// Fallback (round-1 kernel, passes): used only if ws_size is too small.
// ---------------------------------------------------------------------------
__device__ __forceinline__ half8 pack8(const float4& a, const float4& b) {
  half8 r;
  r[0]=(f16)a.x; r[1]=(f16)a.y; r[2]=(f16)a.z; r[3]=(f16)a.w;
  r[4]=(f16)b.x; r[5]=(f16)b.y; r[6]=(f16)b.z; r[7]=(f16)b.w;
  return r;
}

__global__ __launch_bounds__(512, 2)
void chanattn_fallback(const float* __restrict__ x, float* __restrict__ out) {
  __shared__ f16 Pl[BQ * C_];
  const int bi   = blockIdx.x;
  const int slot = bi >> 3;
  const int b    = ((slot >> 4) << 3) | (bi & 7);
  const int rb   = slot & 15;
  const int q0   = rb * BQ;
  const int tid  = threadIdx.x;
  const int w    = tid >> 6;
  const int lane = tid & 63;
  const int l15  = lane & 15;
  const int l4   = lane >> 4;
  const float* mb = x + (size_t)b * (C_ * HW_);
  char* Pb = (char*)Pl;
  {
    const int cw = w * 128;
    for (int tile = 0; tile < 2; ++tile) {
      const int c0 = cw + tile * 64;
      f32x4 acc[4][4] = {};
      for (int kc = 0; kc < NKC; ++kc) {
        const int k0 = kc * 32 + l4 * 8;
        const bool ok = (k0 < HW_);
        half8 afr[4], bfr[4];
#pragma unroll
        for (int rf = 0; rf < 4; ++rf) {
          if (ok) { const float4* p = (const float4*)(mb + (q0 + rf*16 + l15) * HW_ + k0); afr[rf] = pack8(p[0], p[1]); }
          else {
#pragma unroll
            for (int e = 0; e < 8; ++e) afr[rf][e] = (f16)0.f; }
        }
#pragma unroll
        for (int cf = 0; cf < 4; ++cf) {
          if (ok) { const float4* p = (const float4*)(mb + (c0 + cf*16 + l15) * HW_ + k0); bfr[cf] = pack8(p[0], p[1]); }
          else {
#pragma unroll
            for (int e = 0; e < 8; ++e) bfr[cf][e] = (f16)0.f; }
        }
#pragma unroll
        for (int rf = 0; rf < 4; ++rf)
#pragma unroll
          for (int cf = 0; cf < 4; ++cf)
            acc[rf][cf] = __builtin_amdgcn_mfma_f32_16x16x32_f16(afr[rf], bfr[cf], acc[rf][cf], 0, 0, 0);
      }
#pragma unroll
      for (int rf = 0; rf < 4; ++rf)
#pragma unroll
        for (int cf = 0; cf < 4; ++cf)
#pragma unroll
          for (int r = 0; r < 4; ++r) {
            const int row = rf*16 + l4*4 + r;
            const int col = c0 + cf*16 + l15;
            int byte = row*2048 + col*2;
            byte ^= (row & 7) << 4;
            *(f16*)(Pb + byte) = (f16)acc[rf][cf][r];
          }
    }
  }
  __syncthreads();
  {
    const float ksc = 0.045084223f;
    for (int rr = 0; rr < 8; ++rr) {
      const int row = w*8 + rr;
      const int sw  = (row & 7) << 4;
      char* rbase = Pb + row*2048;
      const int c0 = lane * 32;
      half8 v0 = *(half8*)(rbase + ((c0     ) ^ sw));
      half8 v1 = *(half8*)(rbase + ((c0 + 16) ^ sw));
      float f[16];
#pragma unroll
      for (int e = 0; e < 8; ++e) { f[e] = (float)v0[e]; f[e+8] = (float)v1[e]; }
      float mx = f[0];
#pragma unroll
      for (int e = 1; e < 16; ++e) mx = fmaxf(mx, f[e]);
      for (int d = 1; d < 64; d <<= 1) mx = fmaxf(mx, __shfl_xor(mx, d));
      float sum = 0.f;
#pragma unroll
      for (int e = 0; e < 16; ++e) { f[e] = exp2f((f[e] - mx) * ksc); sum += f[e]; }
      for (int d = 1; d < 64; d <<= 1) sum += __shfl_xor(sum, d);
      const float inv = 1.f / sum;
#pragma unroll
      for (int e = 0; e < 8; ++e) { v0[e] = (f16)(f[e]*inv); v1[e] = (f16)(f[e+8]*inv); }
      *(half8*)(rbase + ((c0     ) ^ sw)) = v0;
      *(half8*)(rbase + ((c0 + 16) ^ sw)) = v1;
    }
  }
  __syncthreads();
  {
    f32x4 acc[7][4] = {};
    for (int t = 0; t < 16; ++t) {
      half8 afr[4][2];
#pragma unroll
      for (int rf = 0; rf < 4; ++rf)
#pragma unroll
        for (int kf = 0; kf < 2; ++kf) {
          const int row = rf*16 + l15;
          int byte = row*2048 + t*128 + kf*64 + l4*16;
          byte ^= (row & 7) << 4;
          afr[rf][kf] = *(half8*)(Pb + byte);
        }
#pragma unroll
      for (int si = 0; si < 7; ++si) {
        const int s = w + 8*si;
        if (s < 49) {
          const int d = s*16 + l15;
#pragma unroll
          for (int kf = 0; kf < 2; ++kf) {
            const int kv = t*64 + kf*32 + l4*8;
            half8 bfr;
#pragma unroll
            for (int e = 0; e < 8; ++e) bfr[e] = (f16)mb[(kv + e) * HW_ + d];
#pragma unroll
            for (int rf = 0; rf < 4; ++rf)
              acc[si][rf] = __builtin_amdgcn_mfma_f32_16x16x32_f16(afr[rf][kf], bfr, acc[si][rf], 0, 0, 0);
          }
        }
      }
    }
#pragma unroll
    for (int si = 0; si < 7; ++si) {
      const int s = w + 8*si;
      if (s < 49) {
        const int d = s*16 + l15;
#pragma unroll
        for (int rf = 0; rf < 4; ++rf)
#pragma unroll
          for (int r = 0; r < 4; ++r) {
            const size_t idx = (size_t)(b*C_ + q0 + rf*16 + l4*4 + r) * HW_ + d;
            out[idx] = x[idx] + acc[si][rf][r];
          }
      }
    }
  }
}

extern "C" void kernel_launch(void* const* d_in, const int* in_sizes, int n_in,
                              void* d_out, int out_size, void* d_ws, size_t ws_size,
                              hipStream_t stream) {
  const float* x = (const float*)d_in[0];
  float* out = (float*)d_out;
  const size_t elems = (size_t)B_ * C_ * HW_;          // 25,690,112
  const size_t need  = elems * 2 * 2;                  // m16 + mT, f16
  if (ws_size >= need) {
    f16* m16 = (f16*)d_ws;
    f16* mT  = m16 + elems;
    prep_kernel<<<dim3(32 * 16 * 13), dim3(256), 0, stream>>>(x, m16, mT);
    chanattn_main<<<dim3(512), dim3(512), 0, stream>>>(x, m16, mT, out);
  } else {
    chanattn_fallback<<<dim3(512), dim3(512), 0, stream>>>(x, out);
  }
}

// Round 3
// 299.016 us; speedup vs baseline: 3.7211x; 1.0117x over previous
//
#include <hip/hip_runtime.h>

typedef _Float16 f16;
typedef f16  half8 __attribute__((ext_vector_type(8)));
typedef float f32x4 __attribute__((ext_vector_type(4)));

#define B_   32
#define C_   1024
#define HW_  784
#define BQ   64
#define NKC  25   // ceil(784/32): last chunk lane-masked

// ---------------------------------------------------------------------------
// Prep: m16[b][c][hw] = (f16)x, and mT[b][hw][c] = (f16)x transposed.
// ---------------------------------------------------------------------------
__global__ __launch_bounds__(256)
void prep_kernel(const float* __restrict__ x, f16* __restrict__ m16, f16* __restrict__ mT) {
  __shared__ f16 lt[64][72];   // pad 72: conflict-free transpose
  const int bi = blockIdx.x;               // b*208 + ct*13 + ht
  const int ht = bi % 13;
  const int ct = (bi / 13) & 15;
  const int b  = bi / 208;
  const int h0 = ht * 64, c0 = ct * 64;
  const int t = threadIdx.x, r = t >> 2, q = t & 3;
  const size_t base = (size_t)b * (C_ * HW_);

  const int hq = h0 + q * 16;              // 784 = 49*16: chunks all-or-nothing
  if (hq < HW_) {
    const float* src = x + base + (size_t)(c0 + r) * HW_ + hq;
    float f[16];
#pragma unroll
    for (int j = 0; j < 4; ++j) ((float4*)f)[j] = ((const float4*)src)[j];
    f16 h[16];
#pragma unroll
    for (int j = 0; j < 16; ++j) h[j] = (f16)f[j];
    f16* dm = m16 + base + (size_t)(c0 + r) * HW_ + hq;
    *(half8*)dm = *(half8*)h;
    *(half8*)(dm + 8) = *(half8*)(h + 8);
    *(half8*)&lt[r][q * 16]     = *(half8*)h;
    *(half8*)&lt[r][q * 16 + 8] = *(half8*)(h + 8);
  }
  __syncthreads();
  if (h0 + r < HW_) {
    f16 h[16];
#pragma unroll
    for (int j = 0; j < 16; ++j) h[j] = lt[q * 16 + j][r];
    f16* dst = mT + (size_t)b * (HW_ * C_) + (size_t)(h0 + r) * C_ + c0 + q * 16;
    *(half8*)dst = *(half8*)h;
    *(half8*)(dst + 8) = *(half8*)(h + 8);
  }
}

// ---------------------------------------------------------------------------
// Main fused kernel: per WG = (batch, 64-row block), 16 waves (1024 thr).
// Phase 1: S = m16_rows . m16^T -> raw f16, XOR-swizzled LDS (wave w: cols w*64..)
// Boundary: in-place row softmax (1/32 folded into exp2), 4 rows/wave
// Phase 2: y = P . V (V from mT, contiguous-kv 16B frags); out = x + y
// ---------------------------------------------------------------------------
__global__ __launch_bounds__(1024, 4)
void chanattn_main(const float* __restrict__ x, const f16* __restrict__ m16,
                   const f16* __restrict__ mT, float* __restrict__ out) {
  __shared__ f16 Pl[BQ * C_];   // 128 KiB

  const int bi   = blockIdx.x;
  const int slot = bi >> 3;
  const int b    = ((slot >> 4) << 3) | (bi & 7);   // same-batch WGs share an XCD
  const int rb   = slot & 15;
  const int q0   = rb * BQ;

  const int tid  = threadIdx.x;
  const int w    = tid >> 6;    // 0..15
  const int lane = tid & 63;
  const int l15  = lane & 15;
  const int l4   = lane >> 4;

  const f16* m16b = m16 + (size_t)b * (C_ * HW_);
  const f16* mTb  = mT  + (size_t)b * (HW_ * C_);
  char* Pb = (char*)Pl;

  // ---------------- Phase 1: raw scores (wave w -> 64 cols) ----------------
  {
    const int c0 = w * 64;
    f32x4 acc[4][4] = {};
    for (int kc = 0; kc < NKC; ++kc) {
      const int k0 = kc * 32 + l4 * 8;
      const bool ok = (k0 < HW_);
      half8 afr[4], bfr[4];
#pragma unroll
      for (int rf = 0; rf < 4; ++rf) {
        if (ok) afr[rf] = *(const half8*)(m16b + (size_t)(q0 + rf*16 + l15) * HW_ + k0);
        else {
#pragma unroll
          for (int e = 0; e < 8; ++e) afr[rf][e] = (f16)0.f; }
      }
#pragma unroll
      for (int cf = 0; cf < 4; ++cf) {
        if (ok) bfr[cf] = *(const half8*)(m16b + (size_t)(c0 + cf*16 + l15) * HW_ + k0);
        else {
#pragma unroll
          for (int e = 0; e < 8; ++e) bfr[cf][e] = (f16)0.f; }
      }
#pragma unroll
      for (int rf = 0; rf < 4; ++rf)
#pragma unroll
        for (int cf = 0; cf < 4; ++cf)
          acc[rf][cf] = __builtin_amdgcn_mfma_f32_16x16x32_f16(afr[rf], bfr[cf], acc[rf][cf], 0, 0, 0);
    }
#pragma unroll
    for (int rf = 0; rf < 4; ++rf)
#pragma unroll
      for (int cf = 0; cf < 4; ++cf)
#pragma unroll
        for (int r = 0; r < 4; ++r) {
          const int row = rf*16 + l4*4 + r;     // C/D: col=lane&15, row=(lane>>4)*4+reg
          const int col = c0 + cf*16 + l15;
          int byte = row*2048 + col*2;
          byte ^= (row & 7) << 4;
          *(f16*)(Pb + byte) = (f16)acc[rf][cf][r];
        }
  }
  __syncthreads();

  // ---------------- boundary: softmax, rows w*4..w*4+3 ----------------
  {
    const float ksc = 0.045084223f;   // log2(e)/32
    for (int rr = 0; rr < 4; ++rr) {
      const int row = w*4 + rr;
      const int sw  = (row & 7) << 4;
      char* rbase = Pb + row*2048;
      const int c0 = lane * 32;       // 16 f16 per lane
      half8 v0 = *(half8*)(rbase + ((c0     ) ^ sw));
      half8 v1 = *(half8*)(rbase + ((c0 + 16) ^ sw));
      float f[16];
#pragma unroll
      for (int e = 0; e < 8; ++e) { f[e] = (float)v0[e]; f[e+8] = (float)v1[e]; }
      float mx = f[0];
#pragma unroll
      for (int e = 1; e < 16; ++e) mx = fmaxf(mx, f[e]);
      for (int d = 1; d < 64; d <<= 1) mx = fmaxf(mx, __shfl_xor(mx, d));
      float sum = 0.f;
#pragma unroll
      for (int e = 0; e < 16; ++e) { f[e] = exp2f((f[e] - mx) * ksc); sum += f[e]; }
      for (int d = 1; d < 64; d <<= 1) sum += __shfl_xor(sum, d);
      const float inv = 1.f / sum;
#pragma unroll
      for (int e = 0; e < 8; ++e) { v0[e] = (f16)(f[e]*inv); v1[e] = (f16)(f[e+8]*inv); }
      *(half8*)(rbase + ((c0     ) ^ sw)) = v0;
      *(half8*)(rbase + ((c0 + 16) ^ sw)) = v1;
    }
  }
  __syncthreads();

  // ---------------- Phase 2: y = P . V ; out = x + y ----------------
  {
    f32x4 acc[4][4] = {};   // [d-strip][row-frag]; strips s = w + 16*si over 49
    for (int t = 0; t < 16; ++t) {
      half8 afr[4][2];      // P frags: 64 rows, kv chunk t*64 (two k=32 halves)
#pragma unroll
      for (int rf = 0; rf < 4; ++rf)
#pragma unroll
        for (int kf = 0; kf < 2; ++kf) {
          const int row = rf*16 + l15;          // A: row=lane&15, k=(lane>>4)*8+e
          int byte = row*2048 + t*128 + kf*64 + l4*16;
          byte ^= (row & 7) << 4;
          afr[rf][kf] = *(half8*)(Pb + byte);
        }
#pragma unroll
      for (int si = 0; si < 4; ++si) {
        const int s = w + 16*si;
        if (s < 49) {                            // wave-uniform guard
          const int d = s*16 + l15;
          const f16* vrow = mTb + (size_t)d * C_;
#pragma unroll
          for (int kf = 0; kf < 2; ++kf) {
            const int kv0 = t*64 + kf*32 + l4*8;
            half8 bfr = *(const half8*)(vrow + kv0);   // contiguous in kv
#pragma unroll
            for (int rf = 0; rf < 4; ++rf)
              acc[si][rf] = __builtin_amdgcn_mfma_f32_16x16x32_f16(afr[rf][kf], bfr, acc[si][rf], 0, 0, 0);
          }
        }
      }
    }
#pragma unroll
    for (int si = 0; si < 4; ++si) {
      const int s = w + 16*si;
      if (s < 49) {
        const int d = s*16 + l15;
#pragma unroll
        for (int rf = 0; rf < 4; ++rf)
#pragma unroll
          for (int r = 0; r < 4; ++r) {
            const size_t idx = (size_t)(b*C_ + q0 + rf*16 + l4*4 + r) * HW_ + d;
            out[idx] = x[idx] + acc[si][rf][r];
          }
      }
    }
  }
}

// ---------------------------------------------------------------------------
// Fallback (round-1 kernel, passes standalone): only if ws too small.
// ---------------------------------------------------------------------------
__device__ __forceinline__ half8 pack8(const float4& a, const float4& b) {
  half8 r;
  r[0]=(f16)a.x; r[1]=(f16)a.y; r[2]=(f16)a.z; r[3]=(f16)a.w;
  r[4]=(f16)b.x; r[5]=(f16)b.y; r[6]=(f16)b.z; r[7]=(f16)b.w;
  return r;
}

__global__ __launch_bounds__(512, 2)
void chanattn_fallback(const float* __restrict__ x, float* __restrict__ out) {
  __shared__ f16 Pl[BQ * C_];
  const int bi   = blockIdx.x;
  const int slot = bi >> 3;
  const int b    = ((slot >> 4) << 3) | (bi & 7);
  const int rb   = slot & 15;
  const int q0   = rb * BQ;
  const int tid  = threadIdx.x;
  const int w    = tid >> 6;
  const int lane = tid & 63;
  const int l15  = lane & 15;
  const int l4   = lane >> 4;
  const float* mb = x + (size_t)b * (C_ * HW_);
  char* Pb = (char*)Pl;
  {
    const int cw = w * 128;
    for (int tile = 0; tile < 2; ++tile) {
      const int c0 = cw + tile * 64;
      f32x4 acc[4][4] = {};
      for (int kc = 0; kc < NKC; ++kc) {
        const int k0 = kc * 32 + l4 * 8;
        const bool ok = (k0 < HW_);
        half8 afr[4], bfr[4];
#pragma unroll
        for (int rf = 0; rf < 4; ++rf) {
          if (ok) { const float4* p = (const float4*)(mb + (q0 + rf*16 + l15) * HW_ + k0); afr[rf] = pack8(p[0], p[1]); }
          else {
#pragma unroll
            for (int e = 0; e < 8; ++e) afr[rf][e] = (f16)0.f; }
        }
#pragma unroll
        for (int cf = 0; cf < 4; ++cf) {
          if (ok) { const float4* p = (const float4*)(mb + (c0 + cf*16 + l15) * HW_ + k0); bfr[cf] = pack8(p[0], p[1]); }
          else {
#pragma unroll
            for (int e = 0; e < 8; ++e) bfr[cf][e] = (f16)0.f; }
        }
#pragma unroll
        for (int rf = 0; rf < 4; ++rf)
#pragma unroll
          for (int cf = 0; cf < 4; ++cf)
            acc[rf][cf] = __builtin_amdgcn_mfma_f32_16x16x32_f16(afr[rf], bfr[cf], acc[rf][cf], 0, 0, 0);
      }
#pragma unroll
      for (int rf = 0; rf < 4; ++rf)
#pragma unroll
        for (int cf = 0; cf < 4; ++cf)
#pragma unroll
          for (int r = 0; r < 4; ++r) {
            const int row = rf*16 + l4*4 + r;
            const int col = c0 + cf*16 + l15;
            int byte = row*2048 + col*2;
            byte ^= (row & 7) << 4;
            *(f16*)(Pb + byte) = (f16)acc[rf][cf][r];
          }
    }
  }
  __syncthreads();
  {
    const float ksc = 0.045084223f;
    for (int rr = 0; rr < 8; ++rr) {
      const int row = w*8 + rr;
      const int sw  = (row & 7) << 4;
      char* rbase = Pb + row*2048;
      const int c0 = lane * 32;
      half8 v0 = *(half8*)(rbase + ((c0     ) ^ sw));
      half8 v1 = *(half8*)(rbase + ((c0 + 16) ^ sw));
      float f[16];
#pragma unroll
      for (int e = 0; e < 8; ++e) { f[e] = (float)v0[e]; f[e+8] = (float)v1[e]; }
      float mx = f[0];
#pragma unroll
      for (int e = 1; e < 16; ++e) mx = fmaxf(mx, f[e]);
      for (int d = 1; d < 64; d <<= 1) mx = fmaxf(mx, __shfl_xor(mx, d));
      float sum = 0.f;
#pragma unroll
      for (int e = 0; e < 16; ++e) { f[e] = exp2f((f[e] - mx) * ksc); sum += f[e]; }
      for (int d = 1; d < 64; d <<= 1) sum += __shfl_xor(sum, d);
      const float inv = 1.f / sum;
#pragma unroll
      for (int e = 0; e < 8; ++e) { v0[e] = (f16)(f[e]*inv); v1[e] = (f16)(f[e+8]*inv); }
      *(half8*)(rbase + ((c0     ) ^ sw)) = v0;
      *(half8*)(rbase + ((c0 + 16) ^ sw)) = v1;
    }
  }
  __syncthreads();
  {
    f32x4 acc[7][4] = {};
    for (int t = 0; t < 16; ++t) {
      half8 afr[4][2];
#pragma unroll
      for (int rf = 0; rf < 4; ++rf)
#pragma unroll
        for (int kf = 0; kf < 2; ++kf) {
          const int row = rf*16 + l15;
          int byte = row*2048 + t*128 + kf*64 + l4*16;
          byte ^= (row & 7) << 4;
          afr[rf][kf] = *(half8*)(Pb + byte);
        }
#pragma unroll
      for (int si = 0; si < 7; ++si) {
        const int s = w + 8*si;
        if (s < 49) {
          const int d = s*16 + l15;
#pragma unroll
          for (int kf = 0; kf < 2; ++kf) {
            const int kv = t*64 + kf*32 + l4*8;
            half8 bfr;
#pragma unroll
            for (int e = 0; e < 8; ++e) bfr[e] = (f16)mb[(kv + e) * HW_ + d];
#pragma unroll
            for (int rf = 0; rf < 4; ++rf)
              acc[si][rf] = __builtin_amdgcn_mfma_f32_16x16x32_f16(afr[rf][kf], bfr, acc[si][rf], 0, 0, 0);
          }
        }
      }
    }
#pragma unroll
    for (int si = 0; si < 7; ++si) {
      const int s = w + 8*si;
      if (s < 49) {
        const int d = s*16 + l15;
#pragma unroll
        for (int rf = 0; rf < 4; ++rf)
#pragma unroll
          for (int r = 0; r < 4; ++r) {
            const size_t idx = (size_t)(b*C_ + q0 + rf*16 + l4*4 + r) * HW_ + d;
            out[idx] = x[idx] + acc[si][rf][r];
          }
      }
    }
  }
}

extern "C" void kernel_launch(void* const* d_in, const int* in_sizes, int n_in,
                              void* d_out, int out_size, void* d_ws, size_t ws_size,
                              hipStream_t stream) {
  const float* x = (const float*)d_in[0];
  float* out = (float*)d_out;
  const size_t elems = (size_t)B_ * C_ * HW_;          // 25,690,112
  const size_t need  = elems * 2 * 2;                  // m16 + mT (f16)
  if (ws_size >= need) {
    f16* m16 = (f16*)d_ws;
    f16* mT  = m16 + elems;
    prep_kernel<<<dim3(32 * 16 * 13), dim3(256), 0, stream>>>(x, m16, mT);
    chanattn_main<<<dim3(512), dim3(1024), 0, stream>>>(x, m16, mT, out);
  } else {
    chanattn_fallback<<<dim3(512), dim3(512), 0, stream>>>(x, out);
  }
}